// Round 8
// baseline (30.655 us; speedup 1.0000x reference)
//
#include <hip/hip_runtime.h>
#include <math.h>

#define NB 4
#define FRAMES 400
#define NBINS 129
#define HOP 240
#define T_LEN (FRAMES * HOP)   // 96000
#define KLEN 256               // FIR length = 2*(NBINS-1)

#define REC_C { const float cn_ = fmaf(a2, cm, -cm1); cm1 = cm; cm = cn_; }
#define REC_S { const float sn_ = fmaf(a2, sm, -sm1); sm1 = sm; sm = sn_; }

// broadcast a float from `lane` of the current wave (uniform lane index)
__device__ __forceinline__ float rlane(float v, int lane) {
    return __uint_as_float(__builtin_amdgcn_readlane(__float_as_uint(v), lane));
}

// ---------------------------------------------------------------------------
// Kernel 1: per (b,frame) windowed minimum-phase FIR (256 taps), 128 threads.
// Parity-split (thread n -> ker[n], ker[n+128]); Chebyshev recurrences; HW
// trig in revolutions. NO LDS broadcasts: loop1 coefficients come from global
// via scalar loads; loops 2/3 coefficients come from per-lane registers via
// v_readlane (VALU pipe). LDS is used only for the cross-wave exchange
// (2 writes + 6 strided b32 reads per thread).
// ---------------------------------------------------------------------------
__global__ __launch_bounds__(128) void gen_fir(const float* __restrict__ log_mag,
                                               float* __restrict__ kern) {
    const int bf   = blockIdx.x;    // 0..NB*FRAMES-1
    const int n    = threadIdx.x;   // 0..127
    const int lane = n & 63;

    __shared__ float g[128];        // Xf[k]/128
    __shared__ float crR[128];      // wC[k]   (w=1 at k=0 else 2)
    __shared__ float ciR[128];      // wS[k]

    const float* lm = log_mag + bf * NBINS;   // block-uniform -> s_load

    const float lmn = lm[n];                  // per-lane coalesced
    const float rev_n = (float)n * (1.0f / 256.0f);
    const float ca = __builtin_amdgcn_cosf(rev_n);   // cos(2*pi*n/256)
    const float sa = __builtin_amdgcn_sinf(rev_n);
    const float a2  = 2.0f * ca;
    const float sgn = (n & 1) ? -1.0f : 1.0f;        // (-1)^n

    const float full0   = lm[0];              // uniform scalar
    const float full128 = lm[128];

    // ---- loop1: Xf[n] = 2*sum_{m=0..127} lm[m] cos(mna) - lm[0] + sgn*lm[128]
    {
        float cm1 = ca, cm = 1.0f, acc = 0.0f;       // c_{-1}=cos(-a), c_0=1
#pragma unroll 8
        for (int m = 0; m < 128; ++m) {
            acc = fmaf(lm[m], cm, acc);              // uniform -> SGPR operand
            REC_C;
        }
        g[n] = (2.0f * acc - full0 + sgn * full128) * (1.0f / 128.0f);
    }
    __syncthreads();

    // ---- loop2: mp[n] = -sum_{k=0..127} g[k] sin(kna)  (k=0 term is 0)
    {
        const float gq0 = g[lane], gq1 = g[lane + 64];   // lane-strided, conflict-free
        float sm1 = -sa, sm = 0.0f, acc = 0.0f;          // s_{-1}=sin(-a), s_0=0
        for (int c = 0; c < 8; ++c) {
#pragma unroll
            for (int r = 0; r < 8; ++r) {
                acc = fmaf(rlane(gq0, 8 * c + r), sm, acc); REC_S;
            }
        }
        for (int c = 0; c < 8; ++c) {
#pragma unroll
            for (int r = 0; r < 8; ++r) {
                acc = fmaf(rlane(gq1, 8 * c + r), sm, acc); REC_S;
            }
        }
        const float mp = -acc;
        const float e  = __builtin_amdgcn_exp2f(lmn * 1.4426950408889634f);
        float rev = mp * 0.15915494309189535f;           // mp / (2*pi)
        rev -= floorf(rev);                              // fract reduction
        const float sc = (n == 0) ? 1.0f : 2.0f;
        crR[n] = sc * e * __builtin_amdgcn_cosf(rev);
        ciR[n] = sc * e * __builtin_amdgcn_sinf(rev);
    }
    __syncthreads();

    // ---- loop3: accE (even k), accO (odd k); per k: C[k]cos - S[k]sin
    {
        const float cq0 = crR[lane], cq1 = crR[lane + 64];
        const float sq0 = ciR[lane], sq1 = ciR[lane + 64];
        float cm1 = ca, cm = 1.0f, sm1 = -sa, sm = 0.0f;
        float accE = 0.0f, accO = 0.0f;
        for (int c = 0; c < 8; ++c) {
#pragma unroll
            for (int r = 0; r < 8; r += 2) {
                const int k = 8 * c + r;
                accE = fmaf(rlane(cq0, k), cm, accE);
                accE = fmaf(-rlane(sq0, k), sm, accE);
                REC_C; REC_S;
                accO = fmaf(rlane(cq0, k + 1), cm, accO);
                accO = fmaf(-rlane(sq0, k + 1), sm, accO);
                REC_C; REC_S;
            }
        }
        for (int c = 0; c < 8; ++c) {
#pragma unroll
            for (int r = 0; r < 8; r += 2) {
                const int k = 8 * c + r;
                accE = fmaf(rlane(cq1, k), cm, accE);
                accE = fmaf(-rlane(sq1, k), sm, accE);
                REC_C; REC_S;
                accO = fmaf(rlane(cq1, k + 1), cm, accO);
                accO = fmaf(-rlane(sq1, k + 1), sm, accO);
                REC_C; REC_S;
            }
        }
        const float e128 = __builtin_amdgcn_exp2f(full128 * 1.4426950408889634f);
        const float base = sgn * e128;
        const float s = 1.0f / 256.0f;
        kern[bf * KLEN + n]       = (accE + accO + base) * s;
        kern[bf * KLEN + n + 128] = (accE - accO + base) * s * (0.5f + 0.5f * ca);
    }
}

// ---------------------------------------------------------------------------
// Kernel 2: time-varying FIR, frame-segment-aligned blocks (R6 structure).
// Block bs covers outputs sharing (lo,hi); kernel rows are block-uniform ->
// scalar loads, now CHUNK-PREFETCHED one 8-tap chunk ahead so the lgkmcnt(0)
// drain (SMEM is out-of-order) lands long after issue, overlapped with the
// previous chunk's 4 ds_read_b64 + 32 FMAs. k-values are SGPR FMA operands.
// ---------------------------------------------------------------------------
__global__ __launch_bounds__(128) void fir_apply(const float* __restrict__ ex,
                                                 const float* __restrict__ kern,
                                                 float* __restrict__ out) {
    const int b   = blockIdx.y;
    const int bs  = blockIdx.x;               // 0..400
    const int tid = threadIdx.x;

    const int start = (bs == 0) ? 0 : 240 * bs - 120;
    const int end   = min(T_LEN, 240 * bs + 120);
    const int f     = (bs == 0) ? 0 : bs - 1;
    const int fh    = min(f + 1, FRAMES - 1);

    __shared__ float xs[496];                 // x[start-255 .. start+240]

    const float* xb = ex + b * T_LEN;
    for (int i = tid; i < 496; i += 128) {
        const int t = start - 255 + i;
        xs[i] = (t >= 0 && t < T_LEN) ? xb[t] : 0.0f;
    }
    __syncthreads();

    const int te = start + 2 * tid;
    if (te >= end) return;

    float se = ((float)te + 0.5f) * (1.0f / HOP) - 0.5f;
    se = fminf(fmaxf(se, 0.0f), (float)(FRAMES - 1));
    float so = ((float)te + 1.5f) * (1.0f / HOP) - 0.5f;
    so = fminf(fmaxf(so, 0.0f), (float)(FRAMES - 1));
    const float we = se - (float)f;
    const float wo = so - (float)f;

    const float4* kL4 = (const float4*)(kern + (b * FRAMES + f)  * KLEN);  // uniform
    const float4* kH4 = (const float4*)(kern + (b * FRAMES + fh) * KLEN);  // uniform

    const int base = 2 * tid;                 // xs index of x[te] is base+255
    float carry = xs[base + 256];             // x[te+1]
    float aeL = 0.0f, aeH = 0.0f, aoL = 0.0f, aoH = 0.0f;

    // prefetch chunk 0 (taps 0..7 of both kernels)
    float4 plA = kL4[0], plB = kL4[1], phA = kH4[0], phB = kH4[1];

#pragma unroll 4
    for (int c = 0; c < 32; ++c) {            // 8 taps per chunk
        const float4 klA = plA, klB = plB, khA = phA, khB = phB;
        const int cn = (c + 1) & 31;          // last iter re-fetches chunk 0 (harmless)
        plA = kL4[2 * cn]; plB = kL4[2 * cn + 1];
        phA = kH4[2 * cn]; phB = kH4[2 * cn + 1];

        const int p = base + 248 - 8 * c;     // even -> 8B-aligned b64 reads
        const float2 v0 = *(const float2*)&xs[p];      // x indices p, p+1
        const float2 v1 = *(const float2*)&xs[p + 2];
        const float2 v2 = *(const float2*)&xs[p + 4];
        const float2 v3 = *(const float2*)&xs[p + 6];

        // taps j=8c..8c+7, ascending (same summation order as before)
        aeL = fmaf(v3.y,  klA.x, aeL); aeH = fmaf(v3.y,  khA.x, aeH);
        aoL = fmaf(carry, klA.x, aoL); aoH = fmaf(carry, khA.x, aoH);
        aeL = fmaf(v3.x,  klA.y, aeL); aeH = fmaf(v3.x,  khA.y, aeH);
        aoL = fmaf(v3.y,  klA.y, aoL); aoH = fmaf(v3.y,  khA.y, aoH);
        aeL = fmaf(v2.y,  klA.z, aeL); aeH = fmaf(v2.y,  khA.z, aeH);
        aoL = fmaf(v3.x,  klA.z, aoL); aoH = fmaf(v3.x,  khA.z, aoH);
        aeL = fmaf(v2.x,  klA.w, aeL); aeH = fmaf(v2.x,  khA.w, aeH);
        aoL = fmaf(v2.y,  klA.w, aoL); aoH = fmaf(v2.y,  khA.w, aoH);
        aeL = fmaf(v1.y,  klB.x, aeL); aeH = fmaf(v1.y,  khB.x, aeH);
        aoL = fmaf(v2.x,  klB.x, aoL); aoH = fmaf(v2.x,  khB.x, aoH);
        aeL = fmaf(v1.x,  klB.y, aeL); aeH = fmaf(v1.x,  khB.y, aeH);
        aoL = fmaf(v1.y,  klB.y, aoL); aoH = fmaf(v1.y,  khB.y, aoH);
        aeL = fmaf(v0.y,  klB.z, aeL); aeH = fmaf(v0.y,  khB.z, aeH);
        aoL = fmaf(v1.x,  klB.z, aoL); aoH = fmaf(v1.x,  khB.z, aoH);
        aeL = fmaf(v0.x,  klB.w, aeL); aeH = fmaf(v0.x,  khB.w, aeH);
        aoL = fmaf(v0.y,  klB.w, aoL); aoH = fmaf(v0.y,  khB.w, aoH);

        carry = v0.x;
    }

    const float y0 = aeL + we * (aeH - aeL);
    const float y1 = aoL + wo * (aoH - aoL);
    *(float2*)(out + b * T_LEN + te) = make_float2(y0, y1);  // te even -> aligned
}

// ---------------------------------------------------------------------------
extern "C" void kernel_launch(void* const* d_in, const int* in_sizes, int n_in,
                              void* d_out, int out_size, void* d_ws, size_t ws_size,
                              hipStream_t stream) {
    const float* ex      = (const float*)d_in[0];
    const float* log_mag = (const float*)d_in[1];
    float* kern = (float*)d_ws;          // NB*FRAMES*KLEN floats = 1.6 MB
    float* out  = (float*)d_out;

    gen_fir<<<NB * FRAMES, 128, 0, stream>>>(log_mag, kern);

    dim3 grid(401, NB);                  // 401 frame-aligned segments per batch
    fir_apply<<<grid, 128, 0, stream>>>(ex, kern, out);
}